// Round 1
// baseline (548.337 us; speedup 1.0000x reference)
//
#include <hip/hip_runtime.h>
#include <cstdint>
#include <cstddef>

// Problem geometry (fixed by reference): B=32, C=3, H=384, W=512
#define HW 196608                 // 384*512
#define NBATCH 32
#define NPIX (NBATCH*HW)          // 6,291,456
#define BLOCKS_PER_ROW (HW/256)   // 768 (HW divisible by 256 -> every block lies in one row)
#define NBLOCKS (NPIX/256)        // 24,576
#define PID 98304u                // int(N * 0.5), N = HW
#define THRESHF 0.1f

// Order-preserving float <-> uint key (total order; no NaNs occur here)
__device__ __forceinline__ uint32_t f2key(float f) {
  uint32_t b = __float_as_uint(f);
  return b ^ ((b & 0x80000000u) ? 0xFFFFFFFFu : 0x80000000u);
}
__device__ __forceinline__ float key2f(uint32_t k) {
  uint32_t b = (k & 0x80000000u) ? (k ^ 0x80000000u) : ~k;
  return __uint_as_float(b);
}

// Pass 0: compute theta per pixel, store to ws, and build per-row histogram of top 8 key bits.
// NOTE: reference clamps dp to +/-(1-eps) in fp32 BEFORE acos_safe, and acos_safe's branch
// test uses the same fp32 constant with <=, so the linearized branch is dead code:
// theta == acosf(clamped dp) exactly.
__global__ __launch_bounds__(256) void ep_theta_hist0(
    const float* __restrict__ yhat, const float* __restrict__ yt,
    float* __restrict__ theta, uint32_t* __restrict__ hist0) {
  __shared__ uint32_t h[256];
  const int t = threadIdx.x;
  h[t] = 0;
  __syncthreads();
  const int p  = blockIdx.x * 256 + t;
  const int b  = blockIdx.x / BLOCKS_PER_ROW;
  const int hw = p - b * HW;
  const size_t base = (size_t)b * 3 * HW + hw;
  float a0 = yhat[base], a1 = yhat[base + HW], a2 = yhat[base + 2 * HW];
  float t0 = yt[base],   t1 = yt[base + HW],   t2 = yt[base + 2 * HW];
  float mag = sqrtf(a0 * a0 + a1 * a1 + a2 * a2);
  float dp  = (a0 / mag) * t0 + (a1 / mag) * t1 + (a2 / mag) * t2;
  const float CHI = (float)( 1.0 - 1e-7);  // fp32(0.9999999) = 0x3F7FFFFE
  const float CLO = (float)(-1.0 + 1e-7);
  dp = fminf(fmaxf(dp, CLO), CHI);
  float th = acosf(dp);
  theta[p] = th;
  atomicAdd(&h[f2key(th) >> 24], 1u);
  __syncthreads();
  if (h[t]) atomicAdd(&hist0[(size_t)b * 256 + t], h[t]);
}

// Radix histogram pass: among elements whose key matches prefix on `mask` bits,
// histogram the 8-bit digit at `shift`.
__global__ __launch_bounds__(256) void ep_radix_pass(
    const float* __restrict__ theta, const uint32_t* __restrict__ prefix,
    uint32_t* __restrict__ hist, uint32_t mask, int shift) {
  __shared__ uint32_t h[256];
  const int t = threadIdx.x;
  h[t] = 0;
  __syncthreads();
  const int p = blockIdx.x * 256 + t;
  const int b = blockIdx.x / BLOCKS_PER_ROW;
  const uint32_t key  = f2key(theta[p]);
  const uint32_t pref = prefix[b];
  if ((key & mask) == pref) atomicAdd(&h[(key >> shift) & 0xFFu], 1u);
  __syncthreads();
  if (h[t]) atomicAdd(&hist[(size_t)b * 256 + t], h[t]);
}

// Scan one 256-bin histogram per row; find the bin containing the k-th element,
// update remaining-k and extend the prefix.
__global__ void ep_scan_hist(const uint32_t* __restrict__ hist,
                             uint32_t* __restrict__ prefix, uint32_t* __restrict__ krem,
                             int shift, int first) {
  const int b = threadIdx.x;
  if (b >= NBATCH) return;
  uint32_t k = first ? PID : krem[b];
  const uint32_t* h = hist + (size_t)b * 256;
  uint32_t cum = 0;
  int bin = 255;  // guaranteed found before end (total count > k by construction)
  for (int i = 0; i < 256; i++) {
    uint32_t c = h[i];
    if (cum + c > k) { bin = i; break; }
    cum += c;
  }
  krem[b] = k - cum;
  uint32_t pref = first ? 0u : prefix[b];
  prefix[b] = pref | ((uint32_t)bin << shift);
}

// Final data pass: per row, count/sum of elements strictly below the k-th key,
// and sum of elements < THRESH.
__global__ __launch_bounds__(256) void ep_finalize(
    const float* __restrict__ theta, const uint32_t* __restrict__ kthkey,
    double* __restrict__ sum_less, double* __restrict__ sum_thr,
    uint32_t* __restrict__ cnt_less) {
  const int t = threadIdx.x;
  const int p = blockIdx.x * 256 + t;
  const int b = blockIdx.x / BLOCKS_PER_ROW;
  const float f = theta[p];
  const uint32_t key = f2key(f);
  const uint32_t kk  = kthkey[b];
  double sl = (key < kk) ? (double)f : 0.0;
  double st = (f < THRESHF) ? (double)f : 0.0;
  uint32_t cl = (key < kk) ? 1u : 0u;
  // wave (64-lane) reduction
  for (int off = 32; off; off >>= 1) {
    sl += __shfl_down(sl, off);
    st += __shfl_down(st, off);
    cl += __shfl_down(cl, off);
  }
  __shared__ double s_sl[4], s_st[4];
  __shared__ uint32_t s_cl[4];
  const int wave = t >> 6, lane = t & 63;
  if (lane == 0) { s_sl[wave] = sl; s_st[wave] = st; s_cl[wave] = cl; }
  __syncthreads();
  if (t == 0) {
    double SL = s_sl[0] + s_sl[1] + s_sl[2] + s_sl[3];
    double ST = s_st[0] + s_st[1] + s_st[2] + s_st[3];
    uint32_t CL = s_cl[0] + s_cl[1] + s_cl[2] + s_cl[3];
    atomicAdd(&sum_less[b], SL);
    atomicAdd(&sum_thr[b], ST);
    atomicAdd(&cnt_less[b], CL);
  }
}

// Combine per-row results into the scalar output.
__global__ void ep_out(const uint32_t* __restrict__ kthkey,
                       const double* __restrict__ sum_less, const double* __restrict__ sum_thr,
                       const uint32_t* __restrict__ cnt_less, float* __restrict__ out) {
  const int b = threadIdx.x;  // one wave of 64; rows on lanes 0..31
  double v = 0.0;
  if (b < NBATCH) {
    float fk = key2f(kthkey[b]);
    bool cond = fk < THRESHF;  // vals[:, pid] < THRESH
    if (cond) {
      // sum of smallest PID values = sum(strictly less) + ties filling remaining slots
      v = sum_less[b] + (double)(PID - cnt_less[b]) * (double)fk;
    } else {
      v = sum_thr[b];
    }
  }
  for (int off = 32; off; off >>= 1) v += __shfl_down(v, off);
  if (b == 0) out[0] = (float)v;
}

extern "C" void kernel_launch(void* const* d_in, const int* in_sizes, int n_in,
                              void* d_out, int out_size, void* d_ws, size_t ws_size,
                              hipStream_t stream) {
  const float* yhat = (const float*)d_in[0];
  const float* yt   = (const float*)d_in[1];
  float* out = (float*)d_out;

  // ws layout (needs ~25.3 MB):
  //   theta[NPIX] f32 | sum_less[32] f64 | sum_thr[32] f64 |
  //   hist[4][32][256] u32 | prefix[32] u32 | krem[32] u32 | cnt_less[32] u32
  char* w = (char*)d_ws;
  float*    theta    = (float*)w;
  double*   sum_less = (double*)(w + (size_t)NPIX * 4);
  double*   sum_thr  = sum_less + NBATCH;
  uint32_t* hist     = (uint32_t*)(sum_thr + NBATCH);
  uint32_t* prefix   = hist + 4 * NBATCH * 256;
  uint32_t* krem     = prefix + NBATCH;
  uint32_t* cnt_less = krem + NBATCH;

  // zero the state region (ws is poisoned 0xAA before every launch)
  const size_t state_bytes = 2 * NBATCH * sizeof(double)
                           + (4 * NBATCH * 256 + 3 * NBATCH) * sizeof(uint32_t);
  hipMemsetAsync(w + (size_t)NPIX * 4, 0, state_bytes, stream);

  ep_theta_hist0<<<NBLOCKS, 256, 0, stream>>>(yhat, yt, theta, hist);
  ep_scan_hist<<<1, 64, 0, stream>>>(hist, prefix, krem, 24, 1);

  ep_radix_pass<<<NBLOCKS, 256, 0, stream>>>(theta, prefix, hist + 1 * NBATCH * 256,
                                             0xFF000000u, 16);
  ep_scan_hist<<<1, 64, 0, stream>>>(hist + 1 * NBATCH * 256, prefix, krem, 16, 0);

  ep_radix_pass<<<NBLOCKS, 256, 0, stream>>>(theta, prefix, hist + 2 * NBATCH * 256,
                                             0xFFFF0000u, 8);
  ep_scan_hist<<<1, 64, 0, stream>>>(hist + 2 * NBATCH * 256, prefix, krem, 8, 0);

  ep_radix_pass<<<NBLOCKS, 256, 0, stream>>>(theta, prefix, hist + 3 * NBATCH * 256,
                                             0xFFFFFF00u, 0);
  ep_scan_hist<<<1, 64, 0, stream>>>(hist + 3 * NBATCH * 256, prefix, krem, 0, 0);

  // prefix[] now holds the exact key of the pid-th order statistic per row
  ep_finalize<<<NBLOCKS, 256, 0, stream>>>(theta, prefix, sum_less, sum_thr, cnt_less);
  ep_out<<<1, 64, 0, stream>>>(prefix, sum_less, sum_thr, cnt_less, out);
}

// Round 2
// 243.425 us; speedup vs baseline: 2.2526x; 2.2526x over previous
//
#include <hip/hip_runtime.h>
#include <cstdint>
#include <cstddef>

// Geometry fixed by reference: B=32, C=3, H=384, W=512
#define HW 196608
#define NBATCH 32
#define NPIX (NBATCH*HW)          // 6,291,456
#define PID 98304u                // int(HW * 0.5)
#define THRESHF 0.1f
#define BLOCKS_PER_ROW 192        // HW / (256 threads * 4 px)
#define NBLOCKS (NBATCH*BLOCKS_PER_ROW)  // 6144
#define SC 4294967296.0           // 2^32 fixed-point scale
#define INVSC (1.0/4294967296.0)

// Order-preserving float <-> uint key (no NaNs here: dp clamped before acos)
__device__ __forceinline__ uint32_t f2key(float f) {
  uint32_t b = __float_as_uint(f);
  return b ^ ((b & 0x80000000u) ? 0xFFFFFFFFu : 0x80000000u);
}
__device__ __forceinline__ float key2f(uint32_t k) {
  uint32_t b = (k & 0x80000000u) ? (k ^ 0x80000000u) : ~k;
  return __uint_as_float(b);
}

// Pass 0: theta per pixel (float4-vectorized), write theta, level-0 histogram
// (11 bits: key>>21) counts + fixed-point sums, plus selection-independent
// sum_thr (sum of theta < 0.1) per row.
// Dead-code note: reference clamps dp to +/-(1-eps) fp32 BEFORE acos_safe and
// the branch test uses the same constant with <=, so theta == acosf(clamp(dp)).
__global__ __launch_bounds__(256) void ep_pass0(
    const float* __restrict__ yhat, const float* __restrict__ yt,
    float* __restrict__ theta,
    uint32_t* __restrict__ cnt0, unsigned long long* __restrict__ sum0,
    unsigned long long* __restrict__ thrsum) {
  __shared__ uint32_t hc[2048];
  __shared__ unsigned long long hs[2048];
  __shared__ float wthr[4];
  const int t = threadIdx.x;
  for (int i = t; i < 2048; i += 256) { hc[i] = 0; hs[i] = 0; }
  __syncthreads();
  const int b = blockIdx.x / BLOCKS_PER_ROW;
  const int inRow = blockIdx.x - b * BLOCKS_PER_ROW;
  const int hw = inRow * 1024 + t * 4;
  const float* yb = yhat + (size_t)b * 3 * HW + hw;
  const float* tb = yt   + (size_t)b * 3 * HW + hw;
  float4 a0 = *(const float4*)(yb);
  float4 a1 = *(const float4*)(yb + HW);
  float4 a2 = *(const float4*)(yb + 2 * HW);
  float4 t0 = *(const float4*)(tb);
  float4 t1 = *(const float4*)(tb + HW);
  float4 t2 = *(const float4*)(tb + 2 * HW);
  const float CHI = (float)( 1.0 - 1e-7);
  const float CLO = (float)(-1.0 + 1e-7);
  float4 th4;
  float sthr = 0.f;
#pragma unroll
  for (int j = 0; j < 4; j++) {
    float x0 = (&a0.x)[j], x1 = (&a1.x)[j], x2 = (&a2.x)[j];
    float y0 = (&t0.x)[j], y1 = (&t1.x)[j], y2 = (&t2.x)[j];
    float mag = sqrtf(x0 * x0 + x1 * x1 + x2 * x2);
    float dp = (x0 / mag) * y0 + (x1 / mag) * y1 + (x2 / mag) * y2;
    dp = fminf(fmaxf(dp, CLO), CHI);
    float th = acosf(dp);
    (&th4.x)[j] = th;
    uint32_t key = f2key(th);
    atomicAdd(&hc[key >> 21], 1u);
    atomicAdd(&hs[key >> 21], (unsigned long long)((double)th * SC));
    if (th < THRESHF) sthr += th;
  }
  *(float4*)(theta + (size_t)b * HW + hw) = th4;
  for (int off = 32; off; off >>= 1) sthr += __shfl_down(sthr, off);
  if ((t & 63) == 0) wthr[t >> 6] = sthr;
  __syncthreads();   // also makes all LDS hist atomics visible
  if (t == 0) {
    float bt = wthr[0] + wthr[1] + wthr[2] + wthr[3];
    if (bt != 0.f) atomicAdd(&thrsum[b], (unsigned long long)((double)bt * SC));
  }
  for (int i = t; i < 2048; i += 256) {
    uint32_t c = hc[i];
    if (c) {
      atomicAdd(&cnt0[b * 2048 + i], c);
      atomicAdd(&sum0[b * 2048 + i], hs[i]);
    }
  }
}

// Radix histogram over theta (float4-vectorized): among keys whose top bits
// (>>matchShift) match keyp[b], histogram the next digit; counts + fixed sums.
template <int NBINS>
__global__ __launch_bounds__(256) void ep_radix(
    const float* __restrict__ theta, const uint32_t* __restrict__ keyp,
    uint32_t* __restrict__ cnt, unsigned long long* __restrict__ sum,
    int matchShift, int digShift) {
  __shared__ uint32_t hc[NBINS];
  __shared__ unsigned long long hs[NBINS];
  const int t = threadIdx.x;
  for (int i = t; i < NBINS; i += 256) { hc[i] = 0; hs[i] = 0; }
  __syncthreads();
  const int b = blockIdx.x / BLOCKS_PER_ROW;
  const int inRow = blockIdx.x - b * BLOCKS_PER_ROW;
  const int hw = inRow * 1024 + t * 4;
  float4 v = *(const float4*)(theta + (size_t)b * HW + hw);
  const uint32_t match = keyp[b] >> matchShift;
#pragma unroll
  for (int j = 0; j < 4; j++) {
    float f = (&v.x)[j];
    uint32_t key = f2key(f);
    if ((key >> matchShift) == match) {
      uint32_t d = (key >> digShift) & (NBINS - 1);
      atomicAdd(&hc[d], 1u);
      atomicAdd(&hs[d], (unsigned long long)((double)f * SC));
    }
  }
  __syncthreads();
  for (int i = t; i < NBINS; i += 256) {
    uint32_t c = hc[i];
    if (c) {
      atomicAdd(&cnt[b * NBINS + i], c);
      atomicAdd(&sum[b * NBINS + i], hs[i]);
    }
  }
}

// Scan one level's per-row histogram: find bin containing the k-th element,
// accumulate below-bin counts/sums, extend key prefix. Grid = 32 rows.
__global__ __launch_bounds__(256) void ep_scan(
    const uint32_t* __restrict__ cnt, const unsigned long long* __restrict__ sum,
    uint32_t* __restrict__ keyp, uint32_t* __restrict__ krem,
    uint32_t* __restrict__ cnt_less, unsigned long long* __restrict__ sum_less,
    int nbins, int shift, int first) {
  const int b = blockIdx.x;
  const int t = threadIdx.x;
  const int bpt = nbins >> 8;  // bins per thread (8 or 4)
  const uint32_t* c = cnt + (size_t)b * nbins;
  const unsigned long long* s = sum + (size_t)b * nbins;
  const int base = t * bpt;
  uint32_t csum = 0; unsigned long long ssum = 0;
  for (int i = 0; i < bpt; i++) { csum += c[base + i]; ssum += s[base + i]; }
  __shared__ uint32_t lc[256];
  __shared__ unsigned long long ls[256];
  lc[t] = csum; ls[t] = ssum;
  __syncthreads();
  uint32_t ci = csum; unsigned long long si = ssum;
  for (int off = 1; off < 256; off <<= 1) {
    uint32_t cp = 0; unsigned long long sp = 0;
    if (t >= off) { cp = lc[t - off]; sp = ls[t - off]; }
    __syncthreads();
    ci += cp; si += sp;
    lc[t] = ci; ls[t] = si;
    __syncthreads();
  }
  const uint32_t cumBefore = ci - csum;            // exclusive prefix
  const unsigned long long sumBefore = si - ssum;
  const uint32_t k = first ? PID : krem[b];
  if (k >= cumBefore && k < ci) {                  // unique owner thread
    uint32_t cb = cumBefore; unsigned long long sb = sumBefore;
    int sel = base;
    for (int i = 0; i < bpt; i++) {
      uint32_t cc = c[base + i];
      if (cb + cc > k) { sel = base + i; break; }
      cb += cc; sb += s[base + i];
    }
    krem[b] = k - cb;
    cnt_less[b] += cb;
    sum_less[b] += sb;
    uint32_t kp = first ? 0u : keyp[b];
    keyp[b] = kp | ((uint32_t)sel << shift);
  }
}

__global__ void ep_out(const uint32_t* __restrict__ keyp,
                       const unsigned long long* __restrict__ sum_less,
                       const unsigned long long* __restrict__ thrsum,
                       const uint32_t* __restrict__ cnt_less,
                       float* __restrict__ out) {
  const int b = threadIdx.x;  // one wave; rows on lanes 0..31
  double v = 0.0;
  if (b < NBATCH) {
    float fk = key2f(keyp[b]);
    if (fk < THRESHF)
      v = (double)sum_less[b] * INVSC + (double)(PID - cnt_less[b]) * (double)fk;
    else
      v = (double)thrsum[b] * INVSC;
  }
  for (int off = 32; off; off >>= 1) v += __shfl_down(v, off);
  if (b == 0) out[0] = (float)v;
}

extern "C" void kernel_launch(void* const* d_in, const int* in_sizes, int n_in,
                              void* d_out, int out_size, void* d_ws, size_t ws_size,
                              hipStream_t stream) {
  const float* yhat = (const float*)d_in[0];
  const float* yt   = (const float*)d_in[1];
  float* out = (float*)d_out;

  char* w = (char*)d_ws;
  float* theta = (float*)w;
  size_t off = (size_t)NPIX * 4;                       // 25,165,824 (8B aligned)
  uint32_t* cnt0 = (uint32_t*)(w + off); off += 32 * 2048 * 4;
  uint32_t* cnt1 = (uint32_t*)(w + off); off += 32 * 2048 * 4;
  uint32_t* cnt2 = (uint32_t*)(w + off); off += 32 * 1024 * 4;
  unsigned long long* sum0 = (unsigned long long*)(w + off); off += 32 * 2048 * 8;
  unsigned long long* sum1 = (unsigned long long*)(w + off); off += 32 * 2048 * 8;
  unsigned long long* sum2 = (unsigned long long*)(w + off); off += 32 * 1024 * 8;
  unsigned long long* sum_less = (unsigned long long*)(w + off); off += 32 * 8;
  unsigned long long* thrsum   = (unsigned long long*)(w + off); off += 32 * 8;
  uint32_t* keyp     = (uint32_t*)(w + off); off += 32 * 4;
  uint32_t* krem     = (uint32_t*)(w + off); off += 32 * 4;
  uint32_t* cnt_less = (uint32_t*)(w + off); off += 32 * 4;

  const size_t state_start = (size_t)NPIX * 4;
  const size_t state_bytes = off - state_start;        // ~1.97 MB
  hipMemsetAsync(w + state_start, 0, state_bytes, stream);

  ep_pass0<<<NBLOCKS, 256, 0, stream>>>(yhat, yt, theta, cnt0, sum0, thrsum);
  ep_scan<<<32, 256, 0, stream>>>(cnt0, sum0, keyp, krem, cnt_less, sum_less,
                                  2048, 21, 1);
  ep_radix<2048><<<NBLOCKS, 256, 0, stream>>>(theta, keyp, cnt1, sum1, 21, 10);
  ep_scan<<<32, 256, 0, stream>>>(cnt1, sum1, keyp, krem, cnt_less, sum_less,
                                  2048, 10, 0);
  ep_radix<1024><<<NBLOCKS, 256, 0, stream>>>(theta, keyp, cnt2, sum2, 10, 0);
  ep_scan<<<32, 256, 0, stream>>>(cnt2, sum2, keyp, krem, cnt_less, sum_less,
                                  1024, 0, 0);
  ep_out<<<1, 64, 0, stream>>>(keyp, sum_less, thrsum, cnt_less, out);
}